// Round 14
// baseline (1047.007 us; speedup 1.0000x reference)
//
#include <hip/hip_runtime.h>
#include <hip/hip_bf16.h>

#define B_ 8
#define L_ 48
#define N_ 207
#define D_ 64
#define KH 8
#define T_ 13          // CP = CUT_SIZE + NO_PROXIES
#define CUTS_ 4
#define ND_ (N_ * D_)        // 13248
#define TND_ (T_ * ND_)      // 172224
#define M_ (B_ * T_ * N_)    // 21528 rows for dense layers
#define GBT_ (4 * B_ * T_)   // 416 generator instances

__device__ __forceinline__ float sigmoidf_(float x) { return 1.f / (1.f + __expf(-x)); }

__global__ void zero_kernel(float* p, int n) {
    int i = blockIdx.x * blockDim.x + threadIdx.x;
    if (i < n) p[i] = 0.f;
}

// ------------------------------------------------- param_gen stage 1: coefs
__global__ void param_coef_kernel(
    const float* __restrict__ h_time, const float* __restrict__ h_space,
    const float* __restrict__ Ttw, const float* __restrict__ Ttb,
    const float* __restrict__ wg_w1, const float* __restrict__ wg_b1,
    const float* __restrict__ wg_w2, const float* __restrict__ wg_b2,
    const float* __restrict__ bg_w1, const float* __restrict__ bg_b1,
    const float* __restrict__ bg_w2, const float* __restrict__ bg_b2,
    float* __restrict__ Coef)
{
    int blk = blockIdx.x;                 // g*(B*T) + b*T + c
    int g = blk / (B_ * T_);
    int rem = blk % (B_ * T_);
    int b = rem / T_, c = rem % T_;
    const float* h = (g < 2) ? h_time : h_space;
    int lane = threadIdx.x;

    __shared__ float mem2[64];
    __shared__ float m1s[64];

    {
        float s = 0.f;
        for (int l = 0; l < L_; ++l)
            s += tanhf(h[(b * L_ + l) * 64 + lane]) * Ttw[(g * T_ + c) * L_ + l];
        mem2[lane] = tanhf(s + Ttb[g * T_ + c]);
    }
    __syncthreads();
    {
        int j = lane & 31;
        bool isW = lane < 32;
        const float* w1 = isW ? wg_w1 : bg_w1;
        const float* b1 = isW ? wg_b1 : bg_b1;
        float s = b1[g * 32 + j];
        #pragma unroll 8
        for (int hh = 0; hh < 64; ++hh) s += mem2[hh] * w1[(g * 32 + j) * 64 + hh];
        m1s[lane] = fmaxf(s, 0.f);
    }
    __syncthreads();
    if (lane < 5 || (lane >= 8 && lane < 13)) {
        bool isW = lane < 5;
        int j = isW ? lane : lane - 8;
        const float* w2 = isW ? wg_w2 : bg_w2;
        const float* b2 = isW ? wg_b2 : bg_b2;
        int base = isW ? 0 : 32;
        float s = b2[g * 5 + j];
        #pragma unroll
        for (int k = 0; k < 32; ++k) s += m1s[base + k] * w2[(g * 5 + j) * 32 + k];
        Coef[blk * 16 + (isW ? j : 8 + j)] = fmaxf(s, 0.f);
    }
}

// ------------------------------------- param_gen stage 2: materialize W / B
#define WTOT (GBT_ * 4096)      // 1,703,936
#define BTOT (GBT_ * 64)        // 26,624
__global__ void param_mat_kernel(
    const float* __restrict__ wg_w3, const float* __restrict__ wg_b3,
    const float* __restrict__ bg_w3, const float* __restrict__ bg_b3,
    const float* __restrict__ Coef,
    float* __restrict__ Wg, float* __restrict__ Bg)
{
    int i = blockIdx.x * blockDim.x + threadIdx.x;
    if (i < WTOT) {
        int idx = i & 4095;              // = d*64+e
        int blk = i >> 12;
        int g = blk / (B_ * T_);
        const float* w3 = &wg_w3[((size_t)g * 4096 + idx) * 5];
        const float* cf = &Coef[blk * 16];
        Wg[i] = wg_b3[g * 4096 + idx]
              + cf[0]*w3[0] + cf[1]*w3[1] + cf[2]*w3[2] + cf[3]*w3[3] + cf[4]*w3[4];
    } else if (i < WTOT + BTOT) {
        int k = i - WTOT;
        int idx = k & 63;
        int blk = k >> 6;
        int g = blk / (B_ * T_);
        const float* w3 = &bg_w3[((size_t)g * 64 + idx) * 5];
        const float* cf = &Coef[blk * 16];
        Bg[k] = bg_b3[g * 64 + idx]
              + cf[8]*w3[0] + cf[9]*w3[1] + cf[10]*w3[2] + cf[11]*w3[3] + cf[12]*w3[4];
    }
}

// ----------------------------------------------- custom linear (round-9 form)
#define NCHUNK 8
#define NROWS 26   // ceil(207/8)
__global__ void lincustom_t1_kernel(
    const float* __restrict__ x, const float* __restrict__ proxies,
    const float* __restrict__ out_prev,
    const float* __restrict__ W0, const float* __restrict__ Bi0,
    const float* __restrict__ W1, const float* __restrict__ Bi1,
    float* __restrict__ Y0, float* __restrict__ Y1, int cut_start, int cut_idx)
{
    int bt = blockIdx.x;  // b*T + t
    int b = bt / T_, t = bt % T_;
    int which = blockIdx.z;
    const float* W  = which ? W1 : W0;
    const float* Bi = which ? Bi1 : Bi0;
    float* Y        = which ? Y1 : Y0;

    __shared__ float w[4096], bb[64];
    int tid = threadIdx.x;
    for (int i = tid; i < 4096; i += blockDim.x)
        w[i] = W[(size_t)bt * 4096 + i];
    if (tid < 64) bb[tid] = Bi[bt * 64 + tid];
    __syncthreads();

    int n0 = blockIdx.y * NROWS;
    int n1 = min(n0 + NROWS, N_);
    const float* xrow_base = (t > 0) ? (x + ((size_t)(b * L_ + cut_start + t - 1) * N_) * D_) : nullptr;
    for (int ne = n0 * 64 + tid; ne < n1 * 64; ne += blockDim.x) {
        int n = ne >> 6, e = ne & 63;
        float s = bb[e];
        if (t == 0) {
            const float4* pp = (const float4*)(proxies + (size_t)cut_idx * ND_ + n * 64);
            const float4* op = (const float4*)(out_prev + (size_t)b * ND_ + n * 64);
            #pragma unroll
            for (int dq = 0; dq < 16; ++dq) {
                float4 xa = pp[dq], xb = op[dq];
                int d = dq * 4;
                s += (xa.x + xb.x) * w[d * 64 + e] + (xa.y + xb.y) * w[(d + 1) * 64 + e]
                   + (xa.z + xb.z) * w[(d + 2) * 64 + e] + (xa.w + xb.w) * w[(d + 3) * 64 + e];
            }
        } else {
            const float4* xr = (const float4*)(xrow_base + (size_t)n * 64);
            #pragma unroll
            for (int dq = 0; dq < 16; ++dq) {
                float4 xv = xr[dq];
                int d = dq * 4;
                s += xv.x * w[d * 64 + e] + xv.y * w[(d + 1) * 64 + e]
                   + xv.z * w[(d + 2) * 64 + e] + xv.w * w[(d + 3) * 64 + e];
            }
        }
        Y[(size_t)bt * ND_ + ne] = s;
    }
}

__global__ void lincustom_kernel(
    const float* __restrict__ X,
    const float* __restrict__ W0, const float* __restrict__ Bi0,
    const float* __restrict__ W1, const float* __restrict__ Bi1,
    float* __restrict__ Y0, float* __restrict__ Y1)
{
    int bt = blockIdx.x;
    int which = blockIdx.z;
    const float* W  = which ? W1 : W0;
    const float* Bi = which ? Bi1 : Bi0;
    float* Y        = which ? Y1 : Y0;

    __shared__ float w[4096], bb[64];
    int tid = threadIdx.x;
    for (int i = tid; i < 4096; i += blockDim.x)
        w[i] = W[(size_t)bt * 4096 + i];
    if (tid < 64) bb[tid] = Bi[bt * 64 + tid];
    __syncthreads();

    int n0 = blockIdx.y * NROWS;
    int n1 = min(n0 + NROWS, N_);
    const float* Xbt = X + (size_t)bt * ND_;
    for (int ne = n0 * 64 + tid; ne < n1 * 64; ne += blockDim.x) {
        int n = ne >> 6, e = ne & 63;
        const float4* xr = (const float4*)(Xbt + (size_t)n * 64);
        float s = bb[e];
        #pragma unroll
        for (int dq = 0; dq < 16; ++dq) {
            float4 xv = xr[dq];
            int d = dq * 4;
            s += xv.x * w[d * 64 + e] + xv.y * w[(d + 1) * 64 + e]
               + xv.z * w[(d + 2) * 64 + e] + xv.w * w[(d + 3) * 64 + e];
        }
        Y[(size_t)bt * ND_ + ne] = s;
    }
}

// ------------------------------------------------------- temporal attention
__global__ void temporal_att_kernel(
    const float* __restrict__ proxies, const float* __restrict__ out_prev,
    const float* __restrict__ klin, const float* __restrict__ vlin,
    const float* __restrict__ rate, float* __restrict__ xatt, int cut_idx)
{
    int i = blockIdx.x * blockDim.x + threadIdx.x;
    if (i >= B_ * N_ * KH * T_) return;
    int r = i % T_;
    int h = (i / T_) % KH;
    int n = (i / (T_ * KH)) % N_;
    int b = i / (T_ * KH * N_);

    float srate = sigmoidf_(rate[0]);
    const float rs8 = 0.35355339059327373f;  // 1/sqrt(8)

    float q[8];
    #pragma unroll
    for (int j = 0; j < 8; ++j)
        q[j] = proxies[(size_t)cut_idx * ND_ + n * 64 + h * 8 + j]
             + out_prev[(size_t)b * ND_ + n * 64 + h * 8 + j];

    float dec = (float)(T_ - r);
    float p[T_], sum = 0.f;
    for (int t = 0; t < T_; ++t) {
        const float* kp = klin + ((size_t)(b * T_ + t)) * ND_ + n * 64 + h * 8;
        float s = 0.f;
        #pragma unroll
        for (int j = 0; j < 8; ++j) s += q[j] * kp[j];
        float sa = sigmoidf_(s * rs8);
        float sg = sigmoidf_(sa * srate * dec);
        float at = tanhf(sa / (1.f + sg));
        p[t] = __expf(at);
        sum += p[t];
    }
    float inv = 1.f / sum;
    float acc[8] = {0,0,0,0,0,0,0,0};
    for (int t = 0; t < T_; ++t) {
        float w = p[t] * inv;
        const float* vp = vlin + ((size_t)(b * T_ + t)) * ND_ + n * 64 + h * 8;
        #pragma unroll
        for (int j = 0; j < 8; ++j) acc[j] += w * vp[j];
    }
    float* op = xatt + ((size_t)(b * T_ + r)) * ND_ + n * 64 + h * 8;
    #pragma unroll
    for (int j = 0; j < 8; ++j) op[j] = acc[j];
}

// ------------------------------------------------------ fused dense-dense
// 64 rows/block: halves per-row weight-staging; 337 blocks -> full residency.
template <int ACT1>
__global__ void dense2_kernel(const float* __restrict__ X,
                              const float* __restrict__ W1, const float* __restrict__ b1,
                              const float* __restrict__ W2, const float* __restrict__ b2,
                              float* __restrict__ Y, int M)
{
    __shared__ float w1[64 * 65], w2[64 * 65];   // w[d*65+e] = W[e*64+d]
    __shared__ float bb1[64], bb2[64];
    __shared__ float xs[64][64];
    __shared__ float in2[64][64];
    int tid = threadIdx.x;
    for (int i = tid; i < 4096; i += 256) {
        int e = i >> 6, d = i & 63;
        w1[d * 65 + e] = W1[i];
        w2[d * 65 + e] = W2[i];
    }
    if (tid < 64) { bb1[tid] = b1[tid]; bb2[tid] = b2[tid]; }
    int row0 = blockIdx.x * 64;
    for (int i = tid; i < 4096; i += 256) {
        int r = i >> 6, d = i & 63;
        int row = row0 + r;
        xs[r][d] = (row < M) ? X[(size_t)row * 64 + d] : 0.f;
    }
    __syncthreads();

    int e = tid & 63;
    int rloc0 = tid >> 6;   // wave id 0..3
    for (int r = rloc0; r < 64; r += 4) {
        float s = bb1[e];
        const float4* xr4 = (const float4*)&xs[r][0];
        #pragma unroll
        for (int dq = 0; dq < 16; ++dq) {
            float4 xv = xr4[dq];
            int d = dq * 4;
            s += xv.x * w1[d * 65 + e] + xv.y * w1[(d + 1) * 65 + e]
               + xv.z * w1[(d + 2) * 65 + e] + xv.w * w1[(d + 3) * 65 + e];
        }
        if (ACT1 == 1) s = fmaxf(s, 0.f);
        else if (ACT1 == 2) s = tanhf(s);
        in2[r][e] = s;
    }
    __syncthreads();
    for (int r = rloc0; r < 64; r += 4) {
        int row = row0 + r;
        if (row >= M) break;
        float o = bb2[e];
        const float4* ir4 = (const float4*)&in2[r][0];
        #pragma unroll
        for (int dq = 0; dq < 16; ++dq) {
            float4 xv = ir4[dq];
            int d = dq * 4;
            o += xv.x * w2[d * 65 + e] + xv.y * w2[(d + 1) * 65 + e]
               + xv.z * w2[(d + 2) * 65 + e] + xv.w * w2[(d + 3) * 65 + e];
        }
        Y[(size_t)row * 64 + e] = o;
    }
}

// -------------------------------------------------------- spatial attention
// 256 threads, 1 query/thread; no-max softmax; XCD-friendly mapping:
// blk = h*(B*T) + bt -> i%8 == bt%8, so all 8 heads of a bt share one XCD L2.
__global__ void spatial_att_kernel(const float* __restrict__ Yq,
                                   const float* __restrict__ Ks, const float* __restrict__ Vs,
                                   float* __restrict__ Out)
{
    int blk = blockIdx.x;
    int bt = blk % (B_ * T_);
    int h = blk / (B_ * T_);
    __shared__ float kl[N_ * 8], vl[N_ * 8];
    int tid = threadIdx.x;
    for (int i = tid; i < N_ * 8; i += blockDim.x) {
        int m = i / 8, j = i % 8;
        kl[i] = Ks[(size_t)bt * ND_ + m * 64 + h * 8 + j];
        vl[i] = Vs[(size_t)bt * ND_ + m * 64 + h * 8 + j];
    }
    __syncthreads();
    const float rs8 = 0.35355339059327373f;
    for (int n = tid; n < N_; n += blockDim.x) {
        float q[8];
        const float* qp = Yq + (size_t)bt * ND_ + n * 64 + h * 8;
        #pragma unroll
        for (int j = 0; j < 8; ++j) q[j] = qp[j] * rs8;
        float sum = 0.f;
        float acc[8] = {0,0,0,0,0,0,0,0};
        for (int m = 0; m < N_; ++m) {
            float s = 0.f;
            #pragma unroll
            for (int j = 0; j < 8; ++j) s += q[j] * kl[m * 8 + j];
            float p = __expf(s);
            sum += p;
            #pragma unroll
            for (int j = 0; j < 8; ++j) acc[j] += p * vl[m * 8 + j];
        }
        float inv = 1.f / sum;
        float* op = Out + (size_t)bt * ND_ + n * 64 + h * 8;
        #pragma unroll
        for (int j = 0; j < 8; ++j) op[j] = acc[j] * inv;
    }
}

// ------------------------------------------------------------- gate + reduce
__global__ void gate_reduce_kernel(const float* __restrict__ O, const float* __restrict__ G2,
                                   float* __restrict__ out_fp32, float* __restrict__ d_out,
                                   int cut_idx)
{
    int i = blockIdx.x * blockDim.x + threadIdx.x;
    if (i >= B_ * ND_) return;
    int b = i / ND_;
    int nd = i % ND_;
    float s = 0.f;
    for (int t = 0; t < T_; ++t) {
        float o = O[((size_t)(b * T_ + t)) * ND_ + nd];
        float g = G2[((size_t)(b * T_ + t)) * ND_ + nd];
        s += o * sigmoidf_(g);
    }
    out_fp32[i] = s;
    d_out[((size_t)b * CUTS_ + cut_idx) * ND_ + nd] = s;
}

// ======================================================================
extern "C" void kernel_launch(void* const* d_in, const int* in_sizes, int n_in,
                              void* d_out, int out_size, void* d_ws, size_t ws_size,
                              hipStream_t stream)
{
    const float* x        = (const float*)d_in[0];
    const float* h_time   = (const float*)d_in[1];
    const float* h_space  = (const float*)d_in[2];
    const float* gen_Tt_w = (const float*)d_in[3];
    const float* gen_Tt_b = (const float*)d_in[4];
    const float* wg_w1    = (const float*)d_in[5];
    const float* wg_b1    = (const float*)d_in[6];
    const float* wg_w2    = (const float*)d_in[7];
    const float* wg_b2    = (const float*)d_in[8];
    const float* wg_w3    = (const float*)d_in[9];
    const float* wg_b3    = (const float*)d_in[10];
    const float* bg_w1    = (const float*)d_in[11];
    const float* bg_b1    = (const float*)d_in[12];
    const float* bg_w2    = (const float*)d_in[13];
    const float* bg_b2    = (const float*)d_in[14];
    const float* bg_w3    = (const float*)d_in[15];
    const float* bg_b3    = (const float*)d_in[16];
    const float* proxies  = (const float*)d_in[17];
    const float* ta_p1_w  = (const float*)d_in[18];
    const float* ta_p1_b  = (const float*)d_in[19];
    const float* ta_p2_w  = (const float*)d_in[20];
    const float* ta_p2_b  = (const float*)d_in[21];
    const float* rate     = (const float*)d_in[22];
    const float* sa_p1_w  = (const float*)d_in[23];
    const float* sa_p1_b  = (const float*)d_in[24];
    const float* sa_p2_w  = (const float*)d_in[25];
    const float* sa_p2_b  = (const float*)d_in[26];
    const float* agg_w1   = (const float*)d_in[27];
    const float* agg_b1   = (const float*)d_in[28];
    const float* agg_w2   = (const float*)d_in[29];
    const float* agg_b2   = (const float*)d_in[30];

    float* outp = (float*)d_out;

    float* ws = (float*)d_ws;
    const size_t S = (size_t)B_ * TND_;             // 1,378,944 floats
    const size_t genW = (size_t)B_ * T_ * 4096;
    const size_t genB = (size_t)B_ * T_ * 64;
    size_t off = 0;
    float* Wg   = ws + off; off += 4 * genW;
    float* Bg   = ws + off; off += 4 * genB;
    float* A    = ws + off; off += S;
    float* Bb   = ws + off; off += S;
    float* C    = ws + off; off += S;
    float* Dd   = ws + off; off += S;
    float* out_fp32 = ws + off; off += (size_t)B_ * ND_;
    float* Coef = ws + off; off += GBT_ * 16;

    zero_kernel<<<(B_ * ND_ + 255) / 256, 256, 0, stream>>>(out_fp32, B_ * ND_);

    param_coef_kernel<<<GBT_, 64, 0, stream>>>(
        h_time, h_space, gen_Tt_w, gen_Tt_b,
        wg_w1, wg_b1, wg_w2, wg_b2,
        bg_w1, bg_b1, bg_w2, bg_b2, Coef);
    param_mat_kernel<<<(WTOT + BTOT + 255) / 256, 256, 0, stream>>>(
        wg_w3, wg_b3, bg_w3, bg_b3, Coef, Wg, Bg);

    const int cut_starts[4] = {0, 12, 24, 36};
    const dim3 lcGrid(B_ * T_, NCHUNK, 2);
    const int d2Grid = (M_ + 63) / 64;   // 337
    const int taGrid = (B_ * N_ * KH * T_ + 255) / 256;

    for (int cut = 0; cut < CUTS_; ++cut) {
        // temporal k (gen0) -> A, v (gen1) -> Bb, from virtual t1
        lincustom_t1_kernel<<<lcGrid, 256, 0, stream>>>(
            x, proxies, out_fp32,
            Wg + 0 * genW, Bg + 0 * genB, Wg + 1 * genW, Bg + 1 * genB,
            A, Bb, cut_starts[cut], cut);
        // temporal attention -> C
        temporal_att_kernel<<<taGrid, 256, 0, stream>>>(
            proxies, out_fp32, A, Bb, rate, C, cut);
        // y = dense(tanh(dense(xatt, p1)), p2) -> Dd
        dense2_kernel<2><<<d2Grid, 256, 0, stream>>>(C, ta_p1_w, ta_p1_b, ta_p2_w, ta_p2_b, Dd, M_);
        // spatial k (gen2) -> A, v (gen3) -> Bb
        lincustom_kernel<<<lcGrid, 256, 0, stream>>>(
            Dd, Wg + 2 * genW, Bg + 2 * genB, Wg + 3 * genW, Bg + 3 * genB, A, Bb);
        // spatial attention (q = Dd) -> C
        spatial_att_kernel<<<B_ * T_ * KH, 256, 0, stream>>>(Dd, A, Bb, C);
        // o = dense(relu(dense(sa_out, p1)), p2) -> Bb
        dense2_kernel<1><<<d2Grid, 256, 0, stream>>>(C, sa_p1_w, sa_p1_b, sa_p2_w, sa_p2_b, Bb, M_);
        // gate pre-sigmoid = dense(relu(dense(o, w1)), w2) -> Dd
        dense2_kernel<1><<<d2Grid, 256, 0, stream>>>(Bb, agg_w1, agg_b1, agg_w2, agg_b2, Dd, M_);
        // out = sum_t o * sigmoid(gate)
        gate_reduce_kernel<<<(B_ * ND_ + 255) / 256, 256, 0, stream>>>(
            Bb, Dd, out_fp32, outp, cut);
    }
}

// Round 15
// 780.392 us; speedup vs baseline: 1.3416x; 1.3416x over previous
//
#include <hip/hip_runtime.h>
#include <hip/hip_bf16.h>

#define B_ 8
#define L_ 48
#define N_ 207
#define D_ 64
#define KH 8
#define T_ 13          // CP = CUT_SIZE + NO_PROXIES
#define CUTS_ 4
#define ND_ (N_ * D_)        // 13248
#define TND_ (T_ * ND_)      // 172224
#define M_ (B_ * T_ * N_)    // 21528 rows for dense layers
#define GBT_ (4 * B_ * T_)   // 416 generator instances

__device__ __forceinline__ float sigmoidf_(float x) { return 1.f / (1.f + __expf(-x)); }

__global__ void zero_kernel(float* p, int n) {
    int i = blockIdx.x * blockDim.x + threadIdx.x;
    if (i < n) p[i] = 0.f;
}

// ------------------------------------------------- param_gen stage 1: coefs
__global__ void param_coef_kernel(
    const float* __restrict__ h_time, const float* __restrict__ h_space,
    const float* __restrict__ Ttw, const float* __restrict__ Ttb,
    const float* __restrict__ wg_w1, const float* __restrict__ wg_b1,
    const float* __restrict__ wg_w2, const float* __restrict__ wg_b2,
    const float* __restrict__ bg_w1, const float* __restrict__ bg_b1,
    const float* __restrict__ bg_w2, const float* __restrict__ bg_b2,
    float* __restrict__ Coef)
{
    int blk = blockIdx.x;                 // g*(B*T) + b*T + c
    int g = blk / (B_ * T_);
    int rem = blk % (B_ * T_);
    int b = rem / T_, c = rem % T_;
    const float* h = (g < 2) ? h_time : h_space;
    int lane = threadIdx.x;

    __shared__ float mem2[64];
    __shared__ float m1s[64];

    {
        float s = 0.f;
        for (int l = 0; l < L_; ++l)
            s += tanhf(h[(b * L_ + l) * 64 + lane]) * Ttw[(g * T_ + c) * L_ + l];
        mem2[lane] = tanhf(s + Ttb[g * T_ + c]);
    }
    __syncthreads();
    {
        int j = lane & 31;
        bool isW = lane < 32;
        const float* w1 = isW ? wg_w1 : bg_w1;
        const float* b1 = isW ? wg_b1 : bg_b1;
        float s = b1[g * 32 + j];
        #pragma unroll 8
        for (int hh = 0; hh < 64; ++hh) s += mem2[hh] * w1[(g * 32 + j) * 64 + hh];
        m1s[lane] = fmaxf(s, 0.f);
    }
    __syncthreads();
    if (lane < 5 || (lane >= 8 && lane < 13)) {
        bool isW = lane < 5;
        int j = isW ? lane : lane - 8;
        const float* w2 = isW ? wg_w2 : bg_w2;
        const float* b2 = isW ? wg_b2 : bg_b2;
        int base = isW ? 0 : 32;
        float s = b2[g * 5 + j];
        #pragma unroll
        for (int k = 0; k < 32; ++k) s += m1s[base + k] * w2[(g * 5 + j) * 32 + k];
        Coef[blk * 16 + (isW ? j : 8 + j)] = fmaxf(s, 0.f);
    }
}

// ------------------------------------- param_gen stage 2: materialize W / B
#define WTOT (GBT_ * 4096)      // 1,703,936
#define BTOT (GBT_ * 64)        // 26,624
__global__ void param_mat_kernel(
    const float* __restrict__ wg_w3, const float* __restrict__ wg_b3,
    const float* __restrict__ bg_w3, const float* __restrict__ bg_b3,
    const float* __restrict__ Coef,
    float* __restrict__ Wg, float* __restrict__ Bg)
{
    int i = blockIdx.x * blockDim.x + threadIdx.x;
    if (i < WTOT) {
        int idx = i & 4095;              // = d*64+e
        int blk = i >> 12;
        int g = blk / (B_ * T_);
        const float* w3 = &wg_w3[((size_t)g * 4096 + idx) * 5];
        const float* cf = &Coef[blk * 16];
        Wg[i] = wg_b3[g * 4096 + idx]
              + cf[0]*w3[0] + cf[1]*w3[1] + cf[2]*w3[2] + cf[3]*w3[3] + cf[4]*w3[4];
    } else if (i < WTOT + BTOT) {
        int k = i - WTOT;
        int idx = k & 63;
        int blk = k >> 6;
        int g = blk / (B_ * T_);
        const float* w3 = &bg_w3[((size_t)g * 64 + idx) * 5];
        const float* cf = &Coef[blk * 16];
        Bg[k] = bg_b3[g * 64 + idx]
              + cf[8]*w3[0] + cf[9]*w3[1] + cf[10]*w3[2] + cf[11]*w3[3] + cf[12]*w3[4];
    }
}

// ----------------------------------------------- custom linear (round-9 form)
#define NCHUNK 8
#define NROWS 26   // ceil(207/8)
__global__ void lincustom_t1_kernel(
    const float* __restrict__ x, const float* __restrict__ proxies,
    const float* __restrict__ out_prev,
    const float* __restrict__ W0, const float* __restrict__ Bi0,
    const float* __restrict__ W1, const float* __restrict__ Bi1,
    float* __restrict__ Y0, float* __restrict__ Y1, int cut_start, int cut_idx)
{
    int bt = blockIdx.x;  // b*T + t
    int b = bt / T_, t = bt % T_;
    int which = blockIdx.z;
    const float* W  = which ? W1 : W0;
    const float* Bi = which ? Bi1 : Bi0;
    float* Y        = which ? Y1 : Y0;

    __shared__ float w[4096], bb[64];
    int tid = threadIdx.x;
    for (int i = tid; i < 4096; i += blockDim.x)
        w[i] = W[(size_t)bt * 4096 + i];
    if (tid < 64) bb[tid] = Bi[bt * 64 + tid];
    __syncthreads();

    int n0 = blockIdx.y * NROWS;
    int n1 = min(n0 + NROWS, N_);
    const float* xrow_base = (t > 0) ? (x + ((size_t)(b * L_ + cut_start + t - 1) * N_) * D_) : nullptr;
    for (int ne = n0 * 64 + tid; ne < n1 * 64; ne += blockDim.x) {
        int n = ne >> 6, e = ne & 63;
        float s = bb[e];
        if (t == 0) {
            const float4* pp = (const float4*)(proxies + (size_t)cut_idx * ND_ + n * 64);
            const float4* op = (const float4*)(out_prev + (size_t)b * ND_ + n * 64);
            #pragma unroll
            for (int dq = 0; dq < 16; ++dq) {
                float4 xa = pp[dq], xb = op[dq];
                int d = dq * 4;
                s += (xa.x + xb.x) * w[d * 64 + e] + (xa.y + xb.y) * w[(d + 1) * 64 + e]
                   + (xa.z + xb.z) * w[(d + 2) * 64 + e] + (xa.w + xb.w) * w[(d + 3) * 64 + e];
            }
        } else {
            const float4* xr = (const float4*)(xrow_base + (size_t)n * 64);
            #pragma unroll
            for (int dq = 0; dq < 16; ++dq) {
                float4 xv = xr[dq];
                int d = dq * 4;
                s += xv.x * w[d * 64 + e] + xv.y * w[(d + 1) * 64 + e]
                   + xv.z * w[(d + 2) * 64 + e] + xv.w * w[(d + 3) * 64 + e];
            }
        }
        Y[(size_t)bt * ND_ + ne] = s;
    }
}

__global__ void lincustom_kernel(
    const float* __restrict__ X,
    const float* __restrict__ W0, const float* __restrict__ Bi0,
    const float* __restrict__ W1, const float* __restrict__ Bi1,
    float* __restrict__ Y0, float* __restrict__ Y1)
{
    int bt = blockIdx.x;
    int which = blockIdx.z;
    const float* W  = which ? W1 : W0;
    const float* Bi = which ? Bi1 : Bi0;
    float* Y        = which ? Y1 : Y0;

    __shared__ float w[4096], bb[64];
    int tid = threadIdx.x;
    for (int i = tid; i < 4096; i += blockDim.x)
        w[i] = W[(size_t)bt * 4096 + i];
    if (tid < 64) bb[tid] = Bi[bt * 64 + tid];
    __syncthreads();

    int n0 = blockIdx.y * NROWS;
    int n1 = min(n0 + NROWS, N_);
    const float* Xbt = X + (size_t)bt * ND_;
    for (int ne = n0 * 64 + tid; ne < n1 * 64; ne += blockDim.x) {
        int n = ne >> 6, e = ne & 63;
        const float4* xr = (const float4*)(Xbt + (size_t)n * 64);
        float s = bb[e];
        #pragma unroll
        for (int dq = 0; dq < 16; ++dq) {
            float4 xv = xr[dq];
            int d = dq * 4;
            s += xv.x * w[d * 64 + e] + xv.y * w[(d + 1) * 64 + e]
               + xv.z * w[(d + 2) * 64 + e] + xv.w * w[(d + 3) * 64 + e];
        }
        Y[(size_t)bt * ND_ + ne] = s;
    }
}

// ------------------------------------------------------- temporal attention
__global__ void temporal_att_kernel(
    const float* __restrict__ proxies, const float* __restrict__ out_prev,
    const float* __restrict__ klin, const float* __restrict__ vlin,
    const float* __restrict__ rate, float* __restrict__ xatt, int cut_idx)
{
    int i = blockIdx.x * blockDim.x + threadIdx.x;
    if (i >= B_ * N_ * KH * T_) return;
    int r = i % T_;
    int h = (i / T_) % KH;
    int n = (i / (T_ * KH)) % N_;
    int b = i / (T_ * KH * N_);

    float srate = sigmoidf_(rate[0]);
    const float rs8 = 0.35355339059327373f;  // 1/sqrt(8)

    float q[8];
    #pragma unroll
    for (int j = 0; j < 8; ++j)
        q[j] = proxies[(size_t)cut_idx * ND_ + n * 64 + h * 8 + j]
             + out_prev[(size_t)b * ND_ + n * 64 + h * 8 + j];

    float dec = (float)(T_ - r);
    float p[T_], sum = 0.f;
    for (int t = 0; t < T_; ++t) {
        const float* kp = klin + ((size_t)(b * T_ + t)) * ND_ + n * 64 + h * 8;
        float s = 0.f;
        #pragma unroll
        for (int j = 0; j < 8; ++j) s += q[j] * kp[j];
        float sa = sigmoidf_(s * rs8);
        float sg = sigmoidf_(sa * srate * dec);
        float at = tanhf(sa / (1.f + sg));
        p[t] = __expf(at);
        sum += p[t];
    }
    float inv = 1.f / sum;
    float acc[8] = {0,0,0,0,0,0,0,0};
    for (int t = 0; t < T_; ++t) {
        float w = p[t] * inv;
        const float* vp = vlin + ((size_t)(b * T_ + t)) * ND_ + n * 64 + h * 8;
        #pragma unroll
        for (int j = 0; j < 8; ++j) acc[j] += w * vp[j];
    }
    float* op = xatt + ((size_t)(b * T_ + r)) * ND_ + n * 64 + h * 8;
    #pragma unroll
    for (int j = 0; j < 8; ++j) op[j] = acc[j];
}

// ------------------------------------------------------ fused dense-dense
// Round-13 proven form: 32 rows/block, 50 KB LDS, grid 673.
template <int ACT1>
__global__ void dense2_kernel(const float* __restrict__ X,
                              const float* __restrict__ W1, const float* __restrict__ b1,
                              const float* __restrict__ W2, const float* __restrict__ b2,
                              float* __restrict__ Y, int M)
{
    __shared__ float w1[64 * 65], w2[64 * 65];   // w[d*65+e] = W[e*64+d]
    __shared__ float bb1[64], bb2[64];
    __shared__ float xs[32][64];
    __shared__ float in2[32][64];
    int tid = threadIdx.x;
    for (int i = tid; i < 4096; i += 256) {
        int e = i >> 6, d = i & 63;
        w1[d * 65 + e] = W1[i];
        w2[d * 65 + e] = W2[i];
    }
    if (tid < 64) { bb1[tid] = b1[tid]; bb2[tid] = b2[tid]; }
    int row0 = blockIdx.x * 32;
    for (int i = tid; i < 2048; i += 256) {
        int r = i >> 6, d = i & 63;
        int row = row0 + r;
        xs[r][d] = (row < M) ? X[(size_t)row * 64 + d] : 0.f;
    }
    __syncthreads();

    int e = tid & 63;
    int rloc0 = tid >> 6;   // wave id 0..3
    for (int r = rloc0; r < 32; r += 4) {
        float s = bb1[e];
        const float4* xr4 = (const float4*)&xs[r][0];
        #pragma unroll
        for (int dq = 0; dq < 16; ++dq) {
            float4 xv = xr4[dq];
            int d = dq * 4;
            s += xv.x * w1[d * 65 + e] + xv.y * w1[(d + 1) * 65 + e]
               + xv.z * w1[(d + 2) * 65 + e] + xv.w * w1[(d + 3) * 65 + e];
        }
        if (ACT1 == 1) s = fmaxf(s, 0.f);
        else if (ACT1 == 2) s = tanhf(s);
        in2[r][e] = s;
    }
    __syncthreads();
    for (int r = rloc0; r < 32; r += 4) {
        int row = row0 + r;
        if (row >= M) break;
        float o = bb2[e];
        const float4* ir4 = (const float4*)&in2[r][0];
        #pragma unroll
        for (int dq = 0; dq < 16; ++dq) {
            float4 xv = ir4[dq];
            int d = dq * 4;
            o += xv.x * w2[d * 65 + e] + xv.y * w2[(d + 1) * 65 + e]
               + xv.z * w2[(d + 2) * 65 + e] + xv.w * w2[(d + 3) * 65 + e];
        }
        Y[(size_t)row * 64 + e] = o;
    }
}

// -------------------------------------------------------- spatial attention
// 256 threads, 1 query/thread; no-max softmax; XCD-friendly mapping:
// blk = h*(B*T) + bt -> i%8 == bt%8, so all 8 heads of a bt share one XCD L2.
__global__ void spatial_att_kernel(const float* __restrict__ Yq,
                                   const float* __restrict__ Ks, const float* __restrict__ Vs,
                                   float* __restrict__ Out)
{
    int blk = blockIdx.x;
    int bt = blk % (B_ * T_);
    int h = blk / (B_ * T_);
    __shared__ float kl[N_ * 8], vl[N_ * 8];
    int tid = threadIdx.x;
    for (int i = tid; i < N_ * 8; i += blockDim.x) {
        int m = i / 8, j = i % 8;
        kl[i] = Ks[(size_t)bt * ND_ + m * 64 + h * 8 + j];
        vl[i] = Vs[(size_t)bt * ND_ + m * 64 + h * 8 + j];
    }
    __syncthreads();
    const float rs8 = 0.35355339059327373f;
    for (int n = tid; n < N_; n += blockDim.x) {
        float q[8];
        const float* qp = Yq + (size_t)bt * ND_ + n * 64 + h * 8;
        #pragma unroll
        for (int j = 0; j < 8; ++j) q[j] = qp[j] * rs8;
        float sum = 0.f;
        float acc[8] = {0,0,0,0,0,0,0,0};
        for (int m = 0; m < N_; ++m) {
            float s = 0.f;
            #pragma unroll
            for (int j = 0; j < 8; ++j) s += q[j] * kl[m * 8 + j];
            float p = __expf(s);
            sum += p;
            #pragma unroll
            for (int j = 0; j < 8; ++j) acc[j] += p * vl[m * 8 + j];
        }
        float inv = 1.f / sum;
        float* op = Out + (size_t)bt * ND_ + n * 64 + h * 8;
        #pragma unroll
        for (int j = 0; j < 8; ++j) op[j] = acc[j] * inv;
    }
}

// ------------------------------------------------------------- gate + reduce
__global__ void gate_reduce_kernel(const float* __restrict__ O, const float* __restrict__ G2,
                                   float* __restrict__ out_fp32, float* __restrict__ d_out,
                                   int cut_idx)
{
    int i = blockIdx.x * blockDim.x + threadIdx.x;
    if (i >= B_ * ND_) return;
    int b = i / ND_;
    int nd = i % ND_;
    float s = 0.f;
    for (int t = 0; t < T_; ++t) {
        float o = O[((size_t)(b * T_ + t)) * ND_ + nd];
        float g = G2[((size_t)(b * T_ + t)) * ND_ + nd];
        s += o * sigmoidf_(g);
    }
    out_fp32[i] = s;
    d_out[((size_t)b * CUTS_ + cut_idx) * ND_ + nd] = s;
}

// ======================================================================
extern "C" void kernel_launch(void* const* d_in, const int* in_sizes, int n_in,
                              void* d_out, int out_size, void* d_ws, size_t ws_size,
                              hipStream_t stream)
{
    const float* x        = (const float*)d_in[0];
    const float* h_time   = (const float*)d_in[1];
    const float* h_space  = (const float*)d_in[2];
    const float* gen_Tt_w = (const float*)d_in[3];
    const float* gen_Tt_b = (const float*)d_in[4];
    const float* wg_w1    = (const float*)d_in[5];
    const float* wg_b1    = (const float*)d_in[6];
    const float* wg_w2    = (const float*)d_in[7];
    const float* wg_b2    = (const float*)d_in[8];
    const float* wg_w3    = (const float*)d_in[9];
    const float* wg_b3    = (const float*)d_in[10];
    const float* bg_w1    = (const float*)d_in[11];
    const float* bg_b1    = (const float*)d_in[12];
    const float* bg_w2    = (const float*)d_in[13];
    const float* bg_b2    = (const float*)d_in[14];
    const float* bg_w3    = (const float*)d_in[15];
    const float* bg_b3    = (const float*)d_in[16];
    const float* proxies  = (const float*)d_in[17];
    const float* ta_p1_w  = (const float*)d_in[18];
    const float* ta_p1_b  = (const float*)d_in[19];
    const float* ta_p2_w  = (const float*)d_in[20];
    const float* ta_p2_b  = (const float*)d_in[21];
    const float* rate     = (const float*)d_in[22];
    const float* sa_p1_w  = (const float*)d_in[23];
    const float* sa_p1_b  = (const float*)d_in[24];
    const float* sa_p2_w  = (const float*)d_in[25];
    const float* sa_p2_b  = (const float*)d_in[26];
    const float* agg_w1   = (const float*)d_in[27];
    const float* agg_b1   = (const float*)d_in[28];
    const float* agg_w2   = (const float*)d_in[29];
    const float* agg_b2   = (const float*)d_in[30];

    float* outp = (float*)d_out;

    float* ws = (float*)d_ws;
    const size_t S = (size_t)B_ * TND_;             // 1,378,944 floats
    const size_t genW = (size_t)B_ * T_ * 4096;
    const size_t genB = (size_t)B_ * T_ * 64;
    size_t off = 0;
    float* Wg   = ws + off; off += 4 * genW;
    float* Bg   = ws + off; off += 4 * genB;
    float* A    = ws + off; off += S;
    float* Bb   = ws + off; off += S;
    float* C    = ws + off; off += S;
    float* Dd   = ws + off; off += S;
    float* out_fp32 = ws + off; off += (size_t)B_ * ND_;
    float* Coef = ws + off; off += GBT_ * 16;

    zero_kernel<<<(B_ * ND_ + 255) / 256, 256, 0, stream>>>(out_fp32, B_ * ND_);

    param_coef_kernel<<<GBT_, 64, 0, stream>>>(
        h_time, h_space, gen_Tt_w, gen_Tt_b,
        wg_w1, wg_b1, wg_w2, wg_b2,
        bg_w1, bg_b1, bg_w2, bg_b2, Coef);
    param_mat_kernel<<<(WTOT + BTOT + 255) / 256, 256, 0, stream>>>(
        wg_w3, wg_b3, bg_w3, bg_b3, Coef, Wg, Bg);

    const int cut_starts[4] = {0, 12, 24, 36};
    const dim3 lcGrid(B_ * T_, NCHUNK, 2);
    const int d2Grid = (M_ + 31) / 32;   // 673
    const int taGrid = (B_ * N_ * KH * T_ + 255) / 256;

    for (int cut = 0; cut < CUTS_; ++cut) {
        // temporal k (gen0) -> A, v (gen1) -> Bb, from virtual t1
        lincustom_t1_kernel<<<lcGrid, 256, 0, stream>>>(
            x, proxies, out_fp32,
            Wg + 0 * genW, Bg + 0 * genB, Wg + 1 * genW, Bg + 1 * genB,
            A, Bb, cut_starts[cut], cut);
        // temporal attention -> C
        temporal_att_kernel<<<taGrid, 256, 0, stream>>>(
            proxies, out_fp32, A, Bb, rate, C, cut);
        // y = dense(tanh(dense(xatt, p1)), p2) -> Dd
        dense2_kernel<2><<<d2Grid, 256, 0, stream>>>(C, ta_p1_w, ta_p1_b, ta_p2_w, ta_p2_b, Dd, M_);
        // spatial k (gen2) -> A, v (gen3) -> Bb
        lincustom_kernel<<<lcGrid, 256, 0, stream>>>(
            Dd, Wg + 2 * genW, Bg + 2 * genB, Wg + 3 * genW, Bg + 3 * genB, A, Bb);
        // spatial attention (q = Dd) -> C
        spatial_att_kernel<<<B_ * T_ * KH, 256, 0, stream>>>(Dd, A, Bb, C);
        // o = dense(relu(dense(sa_out, p1)), p2) -> Bb
        dense2_kernel<1><<<d2Grid, 256, 0, stream>>>(C, sa_p1_w, sa_p1_b, sa_p2_w, sa_p2_b, Bb, M_);
        // gate pre-sigmoid = dense(relu(dense(o, w1)), w2) -> Dd
        dense2_kernel<1><<<d2Grid, 256, 0, stream>>>(Bb, agg_w1, agg_b1, agg_w2, agg_b2, Dd, M_);
        // out = sum_t o * sigmoid(gate)
        gate_reduce_kernel<<<(B_ * ND_ + 255) / 256, 256, 0, stream>>>(
            Bb, Dd, out_fp32, outp, cut);
    }
}